// Round 1
// baseline (224.296 us; speedup 1.0000x reference)
//
#include <hip/hip_runtime.h>
#include <math.h>

#define NPOS  32768      // B*H*W
#define CDIM  128
#define HS    64
#define WSZ   64

__device__ __forceinline__ float gelu_exact(float x) {
    return 0.5f * x * (1.0f + erff(x * 0.70710678118654752f));
}

// ---------------------------------------------------------------------------
// K1: depthwise 3x3 conv (NHWC) + per-block partial BN sums
// grid 512 (= B*H rows), block 256. thread: 4 channels x 8 w-positions
// ---------------------------------------------------------------------------
__global__ __launch_bounds__(256) void k_dwconv(
    const float* __restrict__ inp, const float* __restrict__ dww,
    const float* __restrict__ dwb, float* __restrict__ ydw,
    float* __restrict__ psum, float* __restrict__ psq)
{
    int blk = blockIdx.x;            // b*64 + h
    int b = blk >> 6, h = blk & 63;
    int tid = threadIdx.x;
    int c4 = (tid & 31) * 4;
    int wg = tid >> 5;               // 0..7

    float wreg[4][9];
    #pragma unroll
    for (int cc = 0; cc < 4; ++cc)
        #pragma unroll
        for (int p = 0; p < 9; ++p)
            wreg[cc][p] = dww[(c4 + cc) * 9 + p];
    float bia[4];
    #pragma unroll
    for (int cc = 0; cc < 4; ++cc) bia[cc] = dwb[c4 + cc];

    float s4[4] = {0,0,0,0}, q4[4] = {0,0,0,0};
    const float* ibase = inp + (size_t)(b << 12) * CDIM;

    for (int i = 0; i < 8; ++i) {
        int w = wg + i * 8;
        float acc[4] = {bia[0], bia[1], bia[2], bia[3]};
        #pragma unroll
        for (int ky = 0; ky < 3; ++ky) {
            int yy = h + ky - 1;
            if (yy < 0 || yy >= HS) continue;
            #pragma unroll
            for (int kx = 0; kx < 3; ++kx) {
                int xx = w + kx - 1;
                if (xx < 0 || xx >= WSZ) continue;
                float4 v = *(const float4*)(ibase + (size_t)(yy * 64 + xx) * CDIM + c4);
                int p = ky * 3 + kx;
                acc[0] += v.x * wreg[0][p];
                acc[1] += v.y * wreg[1][p];
                acc[2] += v.z * wreg[2][p];
                acc[3] += v.w * wreg[3][p];
            }
        }
        float4 o = {acc[0], acc[1], acc[2], acc[3]};
        *(float4*)(ydw + ((size_t)(b << 12) + h * 64 + w) * CDIM + c4) = o;
        #pragma unroll
        for (int cc = 0; cc < 4; ++cc) { s4[cc] += acc[cc]; q4[cc] += acc[cc] * acc[cc]; }
    }

    __shared__ float ls[8][128], lq[8][128];
    #pragma unroll
    for (int cc = 0; cc < 4; ++cc) { ls[wg][c4 + cc] = s4[cc]; lq[wg][c4 + cc] = q4[cc]; }
    __syncthreads();
    if (tid < 128) {
        float s = 0.f, q = 0.f;
        #pragma unroll
        for (int r = 0; r < 8; ++r) { s += ls[r][tid]; q += lq[r][tid]; }
        psum[blk * 128 + tid] = s;
        psq [blk * 128 + tid] = q;
    }
}

// ---------------------------------------------------------------------------
// K2: finalize BN stats -> scale/shift per channel. grid 128, block 256.
// ---------------------------------------------------------------------------
__global__ __launch_bounds__(256) void k_bnstats(
    const float* __restrict__ psum, const float* __restrict__ psq,
    const float* __restrict__ gamma, const float* __restrict__ beta,
    float* __restrict__ sc, float* __restrict__ sh)
{
    int c = blockIdx.x;
    int t = threadIdx.x;
    float s = psum[t * 128 + c] + psum[(t + 256) * 128 + c];
    float q = psq [t * 128 + c] + psq [(t + 256) * 128 + c];
    __shared__ float rs[256], rq[256];
    rs[t] = s; rq[t] = q; __syncthreads();
    for (int off = 128; off > 0; off >>= 1) {
        if (t < off) { rs[t] += rs[t + off]; rq[t] += rq[t + off]; }
        __syncthreads();
    }
    if (t == 0) {
        float mean = rs[0] * (1.0f / 32768.0f);
        float var  = rq[0] * (1.0f / 32768.0f) - mean * mean;
        float scale = gamma[c] * rsqrtf(var + 1e-5f);
        sc[c] = scale;
        sh[c] = beta[c] - mean * scale;
    }
}

// ---------------------------------------------------------------------------
// K3: elementwise BN + exact GELU, in place on ydw. grid 4096, block 256.
// ---------------------------------------------------------------------------
__global__ __launch_bounds__(256) void k_bngelu(
    float* __restrict__ ydw, const float* __restrict__ sc, const float* __restrict__ sh)
{
    int idx = blockIdx.x * 256 + threadIdx.x;    // over NPOS*128/4
    int c4 = (idx & 31) * 4;
    float4 v = *(float4*)(ydw + (size_t)idx * 4);
    float4 s = *(const float4*)(sc + c4);
    float4 h = *(const float4*)(sh + c4);
    v.x = gelu_exact(v.x * s.x + h.x);
    v.y = gelu_exact(v.y * s.y + h.y);
    v.z = gelu_exact(v.z * s.z + h.z);
    v.w = gelu_exact(v.w * s.w + h.w);
    *(float4*)(ydw + (size_t)idx * 4) = v;
}

// ---------------------------------------------------------------------------
// Tiled fp32 GEMM: C[N x M] = A[N x K] * B[M x K]^T + bias
// block tile 128x128, 256 threads, 8x8 microtile, BK=16.
// MODE 0: store row-major (ldc). MODE 1: + exact GELU. MODE 2: NCHW transpose.
// ---------------------------------------------------------------------------
template<int KDIM, int MODE>
__global__ __launch_bounds__(256) void k_gemm(
    const float* __restrict__ A, const float* __restrict__ B,
    const float* __restrict__ bias, float* __restrict__ C,
    int M, int ldc)
{
    __shared__ float As[16][132];
    __shared__ float Bs[16][132];

    int tid = threadIdx.x;
    int m0 = blockIdx.x * 128;
    int n0 = blockIdx.y * 128;
    int tx = tid & 15, ty = tid >> 4;
    int arow = tid >> 2;           // 0..63
    int ak4  = (tid & 3) * 4;      // 0,4,8,12

    float acc[8][8];
    #pragma unroll
    for (int i = 0; i < 8; ++i)
        #pragma unroll
        for (int j = 0; j < 8; ++j) acc[i][j] = 0.f;

    for (int kc = 0; kc < KDIM; kc += 16) {
        float4 a0 = *(const float4*)(A + (size_t)(m0 + arow) * KDIM + kc + ak4);
        float4 a1 = *(const float4*)(A + (size_t)(m0 + 64 + arow) * KDIM + kc + ak4);
        int br0 = n0 + arow, br1 = n0 + 64 + arow;
        float4 b0 = make_float4(0,0,0,0), b1 = make_float4(0,0,0,0);
        if (br0 < M) b0 = *(const float4*)(B + (size_t)br0 * KDIM + kc + ak4);
        if (br1 < M) b1 = *(const float4*)(B + (size_t)br1 * KDIM + kc + ak4);

        __syncthreads();
        As[ak4 + 0][arow] = a0.x; As[ak4 + 1][arow] = a0.y;
        As[ak4 + 2][arow] = a0.z; As[ak4 + 3][arow] = a0.w;
        As[ak4 + 0][64 + arow] = a1.x; As[ak4 + 1][64 + arow] = a1.y;
        As[ak4 + 2][64 + arow] = a1.z; As[ak4 + 3][64 + arow] = a1.w;
        Bs[ak4 + 0][arow] = b0.x; Bs[ak4 + 1][arow] = b0.y;
        Bs[ak4 + 2][arow] = b0.z; Bs[ak4 + 3][arow] = b0.w;
        Bs[ak4 + 0][64 + arow] = b1.x; Bs[ak4 + 1][64 + arow] = b1.y;
        Bs[ak4 + 2][64 + arow] = b1.z; Bs[ak4 + 3][64 + arow] = b1.w;
        __syncthreads();

        #pragma unroll
        for (int k = 0; k < 16; ++k) {
            float4 A0 = *(float4*)&As[k][ty * 4];
            float4 A1 = *(float4*)&As[k][64 + ty * 4];
            float4 B0 = *(float4*)&Bs[k][tx * 4];
            float4 B1 = *(float4*)&Bs[k][64 + tx * 4];
            float av[8] = {A0.x, A0.y, A0.z, A0.w, A1.x, A1.y, A1.z, A1.w};
            float bv[8] = {B0.x, B0.y, B0.z, B0.w, B1.x, B1.y, B1.z, B1.w};
            #pragma unroll
            for (int i = 0; i < 8; ++i)
                #pragma unroll
                for (int j = 0; j < 8; ++j)
                    acc[i][j] += av[i] * bv[j];
        }
    }

    if (MODE == 0 || MODE == 1) {
        #pragma unroll
        for (int half = 0; half < 2; ++half) {
            #pragma unroll
            for (int i = 0; i < 4; ++i) {
                int row = m0 + half * 64 + ty * 4 + i;
                #pragma unroll
                for (int jh = 0; jh < 2; ++jh) {
                    int col = n0 + jh * 64 + tx * 4;
                    if (col < M) {
                        float4 bb = *(const float4*)(bias + col);
                        float4 v;
                        v.x = acc[half * 4 + i][jh * 4 + 0] + bb.x;
                        v.y = acc[half * 4 + i][jh * 4 + 1] + bb.y;
                        v.z = acc[half * 4 + i][jh * 4 + 2] + bb.z;
                        v.w = acc[half * 4 + i][jh * 4 + 3] + bb.w;
                        if (MODE == 1) {
                            v.x = gelu_exact(v.x); v.y = gelu_exact(v.y);
                            v.z = gelu_exact(v.z); v.w = gelu_exact(v.w);
                        }
                        *(float4*)(C + (size_t)row * ldc + col) = v;
                    }
                }
            }
        }
    } else {
        // transposed NCHW store: out[(b*128 + col)*4096 + hw]
        int b = m0 >> 12;
        int hwb = m0 & 4095;
        #pragma unroll
        for (int half = 0; half < 2; ++half) {
            #pragma unroll
            for (int jh = 0; jh < 2; ++jh) {
                #pragma unroll
                for (int j = 0; j < 4; ++j) {
                    int col = n0 + jh * 64 + tx * 4 + j;
                    float bb = bias[col];
                    float4 v;
                    v.x = acc[half * 4 + 0][jh * 4 + j] + bb;
                    v.y = acc[half * 4 + 1][jh * 4 + j] + bb;
                    v.z = acc[half * 4 + 2][jh * 4 + j] + bb;
                    v.w = acc[half * 4 + 3][jh * 4 + j] + bb;
                    *(float4*)(C + ((size_t)(b * 128 + col) << 12) + hwb + half * 64 + ty * 4) = v;
                }
            }
        }
    }
}

// ---------------------------------------------------------------------------
// K6: DCNv3 core. thread = (pos, g, 4 channels). grid 4096, block 256.
// fused softmax over 9 logits per (pos,g); bilinear gather from xproj.
// ---------------------------------------------------------------------------
__global__ __launch_bounds__(256) void k_dcn(
    const float* __restrict__ xproj, const float* __restrict__ offs,
    const float* __restrict__ msk, float* __restrict__ dcn)
{
    int u = blockIdx.x * 256 + threadIdx.x;  // N*G*4
    int q = u & 3;
    int pg = u >> 2;
    int g = pg & 7;
    int pos = pg >> 3;
    int b = pos >> 12, hw = pos & 4095, h = hw >> 6, w = hw & 63;

    const float* ml = msk + (size_t)pos * 72 + g * 9;
    float e[9];
    float mx = -1e30f;
    #pragma unroll
    for (int p = 0; p < 9; ++p) { e[p] = ml[p]; mx = fmaxf(mx, e[p]); }
    float ssum = 0.f;
    #pragma unroll
    for (int p = 0; p < 9; ++p) { e[p] = expf(e[p] - mx); ssum += e[p]; }
    float inv = 1.0f / ssum;

    const float* ob = offs + (size_t)pos * 144 + g * 18;
    int ch = g * 16 + q * 4;
    const float* xb = xproj + ch;
    size_t bbase = (size_t)(b << 12);

    float4 acc = {0.f, 0.f, 0.f, 0.f};
    #pragma unroll
    for (int p = 0; p < 9; ++p) {
        float dx = ob[p * 2 + 0];
        float dy = ob[p * 2 + 1];
        float px = (float)(w + (p % 3)) + dx;   // padded-space coords
        float py = (float)(h + (p / 3)) + dy;
        float x0f = floorf(px), y0f = floorf(py);
        float wx = px - x0f, wy = py - y0f;
        int ix = (int)x0f, iy = (int)y0f;

        float4 s00 = {0,0,0,0}, s01 = {0,0,0,0}, s10 = {0,0,0,0}, s11 = {0,0,0,0};
        bool y0v = (iy >= 1 && iy <= 64), y1v = (iy + 1 >= 1 && iy + 1 <= 64);
        bool x0v = (ix >= 1 && ix <= 64), x1v = (ix + 1 >= 1 && ix + 1 <= 64);
        if (y0v && x0v) s00 = *(const float4*)(xb + (bbase + (size_t)(iy - 1) * 64 + (ix - 1)) * 128);
        if (y0v && x1v) s01 = *(const float4*)(xb + (bbase + (size_t)(iy - 1) * 64 + ix) * 128);
        if (y1v && x0v) s10 = *(const float4*)(xb + (bbase + (size_t)iy * 64 + (ix - 1)) * 128);
        if (y1v && x1v) s11 = *(const float4*)(xb + (bbase + (size_t)iy * 64 + ix) * 128);

        float w00 = (1.f - wy) * (1.f - wx), w01 = (1.f - wy) * wx;
        float w10 = wy * (1.f - wx),         w11 = wy * wx;
        float mp = e[p] * inv;
        acc.x += mp * (s00.x * w00 + s01.x * w01 + s10.x * w10 + s11.x * w11);
        acc.y += mp * (s00.y * w00 + s01.y * w01 + s10.y * w10 + s11.y * w11);
        acc.z += mp * (s00.z * w00 + s01.z * w01 + s10.z * w10 + s11.z * w11);
        acc.w += mp * (s00.w * w00 + s01.w * w01 + s10.w * w10 + s11.w * w11);
    }
    *(float4*)(dcn + (size_t)pos * 128 + ch) = acc;
}

// ---------------------------------------------------------------------------
extern "C" void kernel_launch(void* const* d_in, const int* in_sizes, int n_in,
                              void* d_out, int out_size, void* d_ws, size_t ws_size,
                              hipStream_t stream)
{
    const float* inp   = (const float*)d_in[0];
    const float* wproj = (const float*)d_in[1];
    const float* bproj = (const float*)d_in[2];
    const float* dww   = (const float*)d_in[3];
    const float* dwb   = (const float*)d_in[4];
    const float* gamma = (const float*)d_in[5];
    const float* beta  = (const float*)d_in[6];
    const float* woff  = (const float*)d_in[7];
    const float* boff  = (const float*)d_in[8];
    const float* wmask = (const float*)d_in[9];
    const float* bmask = (const float*)d_in[10];
    const float* wfc1  = (const float*)d_in[11];
    const float* bfc1  = (const float*)d_in[12];
    const float* wfc2  = (const float*)d_in[13];
    const float* bfc2  = (const float*)d_in[14];
    float* out = (float*)d_out;
    float* ws  = (float*)d_ws;

    float* xproj = ws;                    // 4,194,304 f
    float* ydw   = ws + 4194304;          // 4,194,304 f  (becomes x1 in place)
    float* offs  = ws + 8388608;          // 4,718,592 f
    float* msk   = ws + 13107200;         // 2,359,296 f  (logits)
    float* dcn   = ws + 15466496;         // 4,194,304 f
    float* psum  = ws + 19660800;         // 65,536 f
    float* psq   = ws + 19726336;         // 65,536 f
    float* scs   = ws + 19791872;         // 128 f
    float* shs   = ws + 19792000;         // 128 f
    float* hdn   = ws;                    // 8,388,608 f (reuses xproj+ydw, dead by fc1)

    k_dwconv<<<512, 256, 0, stream>>>(inp, dww, dwb, ydw, psum, psq);
    k_bnstats<<<128, 256, 0, stream>>>(psum, psq, gamma, beta, scs, shs);
    k_bngelu<<<4096, 256, 0, stream>>>(ydw, scs, shs);
    k_gemm<128, 0><<<dim3(256, 1), 256, 0, stream>>>(inp, wproj, bproj, xproj, 128, 128);
    k_gemm<128, 0><<<dim3(256, 2), 256, 0, stream>>>(ydw, woff, boff, offs, 144, 144);
    k_gemm<128, 0><<<dim3(256, 1), 256, 0, stream>>>(ydw, wmask, bmask, msk, 72, 72);
    k_dcn<<<4096, 256, 0, stream>>>(xproj, offs, msk, dcn);
    k_gemm<128, 1><<<dim3(256, 2), 256, 0, stream>>>(dcn, wfc1, bfc1, hdn, 256, 256);
    k_gemm<256, 2><<<dim3(256, 1), 256, 0, stream>>>(hdn, wfc2, bfc2, out, 128, 128);
}

// Round 2
// 216.434 us; speedup vs baseline: 1.0363x; 1.0363x over previous
//
#include <hip/hip_runtime.h>
#include <math.h>

#define NPOS  32768      // B*H*W
#define CDIM  128
#define HS    64
#define WSZ   64

typedef __bf16 bf8_t  __attribute__((ext_vector_type(8)));
typedef float  f32x4  __attribute__((ext_vector_type(4)));

__device__ __forceinline__ float gelu_exact(float x) {
    return 0.5f * x * (1.0f + erff(x * 0.70710678118654752f));
}

// ---------------------------------------------------------------------------
// K1: depthwise 3x3 conv (NHWC) + per-block partial BN sums
// ---------------------------------------------------------------------------
__global__ __launch_bounds__(256) void k_dwconv(
    const float* __restrict__ inp, const float* __restrict__ dww,
    const float* __restrict__ dwb, float* __restrict__ ydw,
    float* __restrict__ psum, float* __restrict__ psq)
{
    int blk = blockIdx.x;            // b*64 + h
    int b = blk >> 6, h = blk & 63;
    int tid = threadIdx.x;
    int c4 = (tid & 31) * 4;
    int wg = tid >> 5;               // 0..7

    float wreg[4][9];
    #pragma unroll
    for (int cc = 0; cc < 4; ++cc)
        #pragma unroll
        for (int p = 0; p < 9; ++p)
            wreg[cc][p] = dww[(c4 + cc) * 9 + p];
    float bia[4];
    #pragma unroll
    for (int cc = 0; cc < 4; ++cc) bia[cc] = dwb[c4 + cc];

    float s4[4] = {0,0,0,0}, q4[4] = {0,0,0,0};
    const float* ibase = inp + (size_t)(b << 12) * CDIM;

    for (int i = 0; i < 8; ++i) {
        int w = wg + i * 8;
        float acc[4] = {bia[0], bia[1], bia[2], bia[3]};
        #pragma unroll
        for (int ky = 0; ky < 3; ++ky) {
            int yy = h + ky - 1;
            if (yy < 0 || yy >= HS) continue;
            #pragma unroll
            for (int kx = 0; kx < 3; ++kx) {
                int xx = w + kx - 1;
                if (xx < 0 || xx >= WSZ) continue;
                float4 v = *(const float4*)(ibase + (size_t)(yy * 64 + xx) * CDIM + c4);
                int p = ky * 3 + kx;
                acc[0] += v.x * wreg[0][p];
                acc[1] += v.y * wreg[1][p];
                acc[2] += v.z * wreg[2][p];
                acc[3] += v.w * wreg[3][p];
            }
        }
        float4 o = {acc[0], acc[1], acc[2], acc[3]};
        *(float4*)(ydw + ((size_t)(b << 12) + h * 64 + w) * CDIM + c4) = o;
        #pragma unroll
        for (int cc = 0; cc < 4; ++cc) { s4[cc] += acc[cc]; q4[cc] += acc[cc] * acc[cc]; }
    }

    __shared__ float ls[8][128], lq[8][128];
    #pragma unroll
    for (int cc = 0; cc < 4; ++cc) { ls[wg][c4 + cc] = s4[cc]; lq[wg][c4 + cc] = q4[cc]; }
    __syncthreads();
    if (tid < 128) {
        float s = 0.f, q = 0.f;
        #pragma unroll
        for (int r = 0; r < 8; ++r) { s += ls[r][tid]; q += lq[r][tid]; }
        psum[blk * 128 + tid] = s;
        psq [blk * 128 + tid] = q;
    }
}

// ---------------------------------------------------------------------------
// K2: finalize BN stats -> scale/shift per channel.
// ---------------------------------------------------------------------------
__global__ __launch_bounds__(256) void k_bnstats(
    const float* __restrict__ psum, const float* __restrict__ psq,
    const float* __restrict__ gamma, const float* __restrict__ beta,
    float* __restrict__ sc, float* __restrict__ sh)
{
    int c = blockIdx.x;
    int t = threadIdx.x;
    float s = psum[t * 128 + c] + psum[(t + 256) * 128 + c];
    float q = psq [t * 128 + c] + psq [(t + 256) * 128 + c];
    __shared__ float rs[256], rq[256];
    rs[t] = s; rq[t] = q; __syncthreads();
    for (int off = 128; off > 0; off >>= 1) {
        if (t < off) { rs[t] += rs[t + off]; rq[t] += rq[t + off]; }
        __syncthreads();
    }
    if (t == 0) {
        float mean = rs[0] * (1.0f / 32768.0f);
        float var  = rq[0] * (1.0f / 32768.0f) - mean * mean;
        float scale = gamma[c] * rsqrtf(var + 1e-5f);
        sc[c] = scale;
        sh[c] = beta[c] - mean * scale;
    }
}

// ---------------------------------------------------------------------------
// K3: elementwise BN + exact GELU, in place on ydw.
// ---------------------------------------------------------------------------
__global__ __launch_bounds__(256) void k_bngelu(
    float* __restrict__ ydw, const float* __restrict__ sc, const float* __restrict__ sh)
{
    int idx = blockIdx.x * 256 + threadIdx.x;    // over NPOS*128/4
    int c4 = (idx & 31) * 4;
    float4 v = *(float4*)(ydw + (size_t)idx * 4);
    float4 s = *(const float4*)(sc + c4);
    float4 h = *(const float4*)(sh + c4);
    v.x = gelu_exact(v.x * s.x + h.x);
    v.y = gelu_exact(v.y * s.y + h.y);
    v.z = gelu_exact(v.z * s.z + h.z);
    v.w = gelu_exact(v.w * s.w + h.w);
    *(float4*)(ydw + (size_t)idx * 4) = v;
}

// ---------------------------------------------------------------------------
// K_wprep: convert weight matrices W[N][K] (fp32) -> fragment-ordered hi/lo
// bf16 buffers. frag elem: idx = ((kc*NT+t)*64 + lane)*8 + i
//   maps W[t*16 + lane%16][kc*32 + (lane/16)*8 + i]   (zero-padded n>=N)
// hi buffer at [0, UNIT), lo at [UNIT, 2*UNIT), UNIT = KC*NT*512 ushorts.
// ---------------------------------------------------------------------------
__global__ __launch_bounds__(64) void k_wprep(
    const float* __restrict__ w0, const float* __restrict__ w1,
    const float* __restrict__ w2, const float* __restrict__ w3,
    const float* __restrict__ w4, unsigned short* __restrict__ wb)
{
    int bid = blockIdx.x, lane = threadIdx.x;
    const float* W; int N, K, NT; unsigned short* out; int local;
    if (bid < 32)       { W = w0; N = 128; K = 128; NT = 8;  out = wb;          local = bid; }
    else if (bid < 68)  { W = w1; N = 144; K = 128; NT = 9;  out = wb + 32768;  local = bid - 32; }
    else if (bid < 88)  { W = w2; N = 72;  K = 128; NT = 5;  out = wb + 69632;  local = bid - 68; }
    else if (bid < 152) { W = w3; N = 256; K = 128; NT = 16; out = wb + 90112;  local = bid - 88; }
    else                { W = w4; N = 128; K = 256; NT = 8;  out = wb + 155648; local = bid - 152; }
    int KC = K / 32;
    int unit = KC * NT * 512;
    int kc = local / NT, t = local % NT;
    int n  = t * 16 + (lane & 15);
    int kb = kc * 32 + (lane >> 4) * 8;
    size_t base = ((size_t)local * 64 + lane) * 8;
    #pragma unroll
    for (int i = 0; i < 8; ++i) {
        float v = (n < N) ? W[(size_t)n * K + kb + i] : 0.f;
        __bf16 h = (__bf16)v;
        float  r = v - (float)h;
        __bf16 l = (__bf16)r;
        out[base + i]        = __builtin_bit_cast(unsigned short, h);
        out[unit + base + i] = __builtin_bit_cast(unsigned short, l);
    }
}

// ---------------------------------------------------------------------------
// MFMA GEMM: C[M=32768 x NV] = A[M x KDIM] * W[NV x KDIM]^T + bias
// hi/lo bf16 split (3 MFMAs) for ~fp32 accuracy. Weights pre-fragmented.
// block 256 = 4 waves, each wave 32 rows (2 row-tiles); grid 256.
// MODE 0: row-major store. MODE 1: + GELU. MODE 2: NCHW transposed store.
// MODE 0/1 swap operands -> D[n][m], lane stores contiguous float4 along n.
// MODE 2 unswapped -> D[m][n], float4 along m (contiguous hw in NCHW).
// ---------------------------------------------------------------------------
template<int KDIM, int NT, int MODE, int NV>
__global__ __launch_bounds__(256) void k_mgemm(
    const float* __restrict__ A, const unsigned short* __restrict__ WF,
    const float* __restrict__ bias, float* __restrict__ C, int ldc)
{
    constexpr int KC = KDIM / 32;
    constexpr int UNIT = KC * NT * 512;
    int tid = threadIdx.x;
    int lane = tid & 63, w = tid >> 6;
    int rbase = blockIdx.x * 128 + w * 32;
    int lr = lane & 15;
    int lk = (lane >> 4) * 8;

    f32x4 acc[2][NT];
    #pragma unroll
    for (int rt = 0; rt < 2; ++rt)
        #pragma unroll
        for (int t = 0; t < NT; ++t)
            acc[rt][t] = (f32x4){0.f, 0.f, 0.f, 0.f};

    const float* a0 = A + (size_t)(rbase + lr) * KDIM + lk;
    const float* a1 = a0 + (size_t)16 * KDIM;
    const bf8_t* WH = (const bf8_t*)WF;
    const bf8_t* WL = (const bf8_t*)(WF + UNIT);

    float4 xr[2][2][2];  // [buf][rowtile][half]
    xr[0][0][0] = *(const float4*)(a0);
    xr[0][0][1] = *(const float4*)(a0 + 4);
    xr[0][1][0] = *(const float4*)(a1);
    xr[0][1][1] = *(const float4*)(a1 + 4);

    #pragma unroll
    for (int kc = 0; kc < KC; ++kc) {
        int cur = kc & 1;
        if (kc + 1 < KC) {
            int o = (kc + 1) * 32;
            xr[cur ^ 1][0][0] = *(const float4*)(a0 + o);
            xr[cur ^ 1][0][1] = *(const float4*)(a0 + o + 4);
            xr[cur ^ 1][1][0] = *(const float4*)(a1 + o);
            xr[cur ^ 1][1][1] = *(const float4*)(a1 + o + 4);
        }
        bf8_t xh[2], xl[2];
        #pragma unroll
        for (int rt = 0; rt < 2; ++rt) {
            float tmp[8];
            *(float4*)&tmp[0] = xr[cur][rt][0];
            *(float4*)&tmp[4] = xr[cur][rt][1];
            #pragma unroll
            for (int i = 0; i < 8; ++i) {
                __bf16 h = (__bf16)tmp[i];
                xh[rt][i] = h;
                xl[rt][i] = (__bf16)(tmp[i] - (float)h);
            }
        }
        #pragma unroll
        for (int t = 0; t < NT; ++t) {
            bf8_t wh = WH[(kc * NT + t) * 64 + lane];
            bf8_t wl = WL[(kc * NT + t) * 64 + lane];
            #pragma unroll
            for (int rt = 0; rt < 2; ++rt) {
                if (MODE == 2) {
                    acc[rt][t] = __builtin_amdgcn_mfma_f32_16x16x32_bf16(xh[rt], wh, acc[rt][t], 0, 0, 0);
                    acc[rt][t] = __builtin_amdgcn_mfma_f32_16x16x32_bf16(xl[rt], wh, acc[rt][t], 0, 0, 0);
                    acc[rt][t] = __builtin_amdgcn_mfma_f32_16x16x32_bf16(xh[rt], wl, acc[rt][t], 0, 0, 0);
                } else {
                    acc[rt][t] = __builtin_amdgcn_mfma_f32_16x16x32_bf16(wh, xh[rt], acc[rt][t], 0, 0, 0);
                    acc[rt][t] = __builtin_amdgcn_mfma_f32_16x16x32_bf16(wh, xl[rt], acc[rt][t], 0, 0, 0);
                    acc[rt][t] = __builtin_amdgcn_mfma_f32_16x16x32_bf16(wl, xh[rt], acc[rt][t], 0, 0, 0);
                }
            }
        }
    }

    if (MODE == 0 || MODE == 1) {
        // D[n][m]: lane holds m = rbase+rt*16+lr, n = t*16 + (lane>>4)*4 + j
        #pragma unroll
        for (int rt = 0; rt < 2; ++rt) {
            int m = rbase + rt * 16 + lr;
            #pragma unroll
            for (int t = 0; t < NT; ++t) {
                int nb = t * 16 + (lane >> 4) * 4;
                if (nb + 4 <= NV) {
                    float4 bb = *(const float4*)(bias + nb);
                    f32x4 a = acc[rt][t];
                    float4 v = {a[0] + bb.x, a[1] + bb.y, a[2] + bb.z, a[3] + bb.w};
                    if (MODE == 1) {
                        v.x = gelu_exact(v.x); v.y = gelu_exact(v.y);
                        v.z = gelu_exact(v.z); v.w = gelu_exact(v.w);
                    }
                    *(float4*)(C + (size_t)m * ldc + nb) = v;
                }
            }
        }
    } else {
        // D[m][n]: lane holds n = t*16+lr, m = rbase+rt*16+(lane>>4)*4+j
        #pragma unroll
        for (int rt = 0; rt < 2; ++rt) {
            int m4 = rbase + rt * 16 + ((lane >> 4) << 2);
            int b = m4 >> 12, hw = m4 & 4095;
            #pragma unroll
            for (int t = 0; t < NT; ++t) {
                int n = t * 16 + lr;
                float bb = bias[n];
                f32x4 a = acc[rt][t];
                float4 v = {a[0] + bb, a[1] + bb, a[2] + bb, a[3] + bb};
                *(float4*)(C + (((size_t)(b * 128 + n)) << 12) + hw) = v;
            }
        }
    }
}

// ---------------------------------------------------------------------------
// K6: DCNv3 core. thread = (pos, g, 4 channels). grid 4096, block 256.
// ---------------------------------------------------------------------------
__global__ __launch_bounds__(256) void k_dcn(
    const float* __restrict__ xproj, const float* __restrict__ offs,
    const float* __restrict__ msk, float* __restrict__ dcn)
{
    int u = blockIdx.x * 256 + threadIdx.x;  // N*G*4
    int q = u & 3;
    int pg = u >> 2;
    int g = pg & 7;
    int pos = pg >> 3;
    int b = pos >> 12, hw = pos & 4095, h = hw >> 6, w = hw & 63;

    const float* ml = msk + (size_t)pos * 72 + g * 9;
    float e[9];
    float mx = -1e30f;
    #pragma unroll
    for (int p = 0; p < 9; ++p) { e[p] = ml[p]; mx = fmaxf(mx, e[p]); }
    float ssum = 0.f;
    #pragma unroll
    for (int p = 0; p < 9; ++p) { e[p] = expf(e[p] - mx); ssum += e[p]; }
    float inv = 1.0f / ssum;

    const float* ob = offs + (size_t)pos * 144 + g * 18;
    int ch = g * 16 + q * 4;
    const float* xb = xproj + ch;
    size_t bbase = (size_t)(b << 12);

    float4 acc = {0.f, 0.f, 0.f, 0.f};
    #pragma unroll
    for (int p = 0; p < 9; ++p) {
        float dx = ob[p * 2 + 0];
        float dy = ob[p * 2 + 1];
        float px = (float)(w + (p % 3)) + dx;   // padded-space coords
        float py = (float)(h + (p / 3)) + dy;
        float x0f = floorf(px), y0f = floorf(py);
        float wx = px - x0f, wy = py - y0f;
        int ix = (int)x0f, iy = (int)y0f;

        float4 s00 = {0,0,0,0}, s01 = {0,0,0,0}, s10 = {0,0,0,0}, s11 = {0,0,0,0};
        bool y0v = (iy >= 1 && iy <= 64), y1v = (iy + 1 >= 1 && iy + 1 <= 64);
        bool x0v = (ix >= 1 && ix <= 64), x1v = (ix + 1 >= 1 && ix + 1 <= 64);
        if (y0v && x0v) s00 = *(const float4*)(xb + (bbase + (size_t)(iy - 1) * 64 + (ix - 1)) * 128);
        if (y0v && x1v) s01 = *(const float4*)(xb + (bbase + (size_t)(iy - 1) * 64 + ix) * 128);
        if (y1v && x0v) s10 = *(const float4*)(xb + (bbase + (size_t)iy * 64 + (ix - 1)) * 128);
        if (y1v && x1v) s11 = *(const float4*)(xb + (bbase + (size_t)iy * 64 + ix) * 128);

        float w00 = (1.f - wy) * (1.f - wx), w01 = (1.f - wy) * wx;
        float w10 = wy * (1.f - wx),         w11 = wy * wx;
        float mp = e[p] * inv;
        acc.x += mp * (s00.x * w00 + s01.x * w01 + s10.x * w10 + s11.x * w11);
        acc.y += mp * (s00.y * w00 + s01.y * w01 + s10.y * w10 + s11.y * w11);
        acc.z += mp * (s00.z * w00 + s01.z * w01 + s10.z * w10 + s11.z * w11);
        acc.w += mp * (s00.w * w00 + s01.w * w01 + s10.w * w10 + s11.w * w11);
    }
    *(float4*)(dcn + (size_t)pos * 128 + ch) = acc;
}

// ---------------------------------------------------------------------------
extern "C" void kernel_launch(void* const* d_in, const int* in_sizes, int n_in,
                              void* d_out, int out_size, void* d_ws, size_t ws_size,
                              hipStream_t stream)
{
    const float* inp   = (const float*)d_in[0];
    const float* wproj = (const float*)d_in[1];
    const float* bproj = (const float*)d_in[2];
    const float* dww   = (const float*)d_in[3];
    const float* dwb   = (const float*)d_in[4];
    const float* gamma = (const float*)d_in[5];
    const float* beta  = (const float*)d_in[6];
    const float* woff  = (const float*)d_in[7];
    const float* boff  = (const float*)d_in[8];
    const float* wmask = (const float*)d_in[9];
    const float* bmask = (const float*)d_in[10];
    const float* wfc1  = (const float*)d_in[11];
    const float* bfc1  = (const float*)d_in[12];
    const float* wfc2  = (const float*)d_in[13];
    const float* bfc2  = (const float*)d_in[14];
    float* out = (float*)d_out;
    float* ws  = (float*)d_ws;

    float* xproj = ws;                    // 4,194,304 f
    float* ydw   = ws + 4194304;          // 4,194,304 f  (becomes x1 in place)
    float* offs  = ws + 8388608;          // 4,718,592 f
    float* msk   = ws + 13107200;         // 2,359,296 f  (logits)
    float* dcn   = ws + 15466496;         // 4,194,304 f
    float* psum  = ws + 19660800;         // 65,536 f
    float* psq   = ws + 19726336;         // 65,536 f
    float* scs   = ws + 19791872;         // 128 f
    float* shs   = ws + 19792000;         // 128 f
    float* hdn   = ws;                    // 8,388,608 f (reuses xproj+ydw, dead by fc1)
    unsigned short* wfr = (unsigned short*)(ws + 19792128);  // 221,184 ush

    unsigned short* wproj_f = wfr;
    unsigned short* woff_f  = wfr + 32768;
    unsigned short* wmask_f = wfr + 69632;
    unsigned short* wfc1_f  = wfr + 90112;
    unsigned short* wfc2_f  = wfr + 155648;

    k_wprep<<<216, 64, 0, stream>>>(wproj, woff, wmask, wfc1, wfc2, wfr);
    k_dwconv<<<512, 256, 0, stream>>>(inp, dww, dwb, ydw, psum, psq);
    k_bnstats<<<128, 256, 0, stream>>>(psum, psq, gamma, beta, scs, shs);
    k_bngelu<<<4096, 256, 0, stream>>>(ydw, scs, shs);
    k_mgemm<128,  8, 0, 128><<<256, 256, 0, stream>>>(inp, wproj_f, bproj, xproj, 128);
    k_mgemm<128,  9, 0, 144><<<256, 256, 0, stream>>>(ydw, woff_f,  boff,  offs, 144);
    k_mgemm<128,  5, 0,  72><<<256, 256, 0, stream>>>(ydw, wmask_f, bmask, msk,   72);
    k_dcn<<<4096, 256, 0, stream>>>(xproj, offs, msk, dcn);
    k_mgemm<128, 16, 1, 256><<<256, 256, 0, stream>>>(dcn, wfc1_f, bfc1, hdn, 256);
    k_mgemm<256,  8, 2, 128><<<256, 256, 0, stream>>>(hdn, wfc2_f, bfc2, out, 128);
}

// Round 3
// 170.225 us; speedup vs baseline: 1.3176x; 1.2715x over previous
//
#include <hip/hip_runtime.h>
#include <math.h>

#define NPOS  32768      // B*H*W
#define CDIM  128
#define HS    64
#define WSZ   64

typedef __bf16 bf8_t  __attribute__((ext_vector_type(8)));
typedef float  f32x4  __attribute__((ext_vector_type(4)));

__device__ __forceinline__ float gelu_exact(float x) {
    return 0.5f * x * (1.0f + erff(x * 0.70710678118654752f));
}

__device__ __forceinline__ void hilo(float v, unsigned& h, unsigned& l) {
    __bf16 hb = (__bf16)v;
    h = (unsigned)__builtin_bit_cast(unsigned short, hb);
    __bf16 lb = (__bf16)(v - (float)hb);
    l = (unsigned)__builtin_bit_cast(unsigned short, lb);
}

__device__ __forceinline__ void pack8(const float* v, uint4& hi, uint4& lo) {
    unsigned hh[8], ll[8];
    #pragma unroll
    for (int i = 0; i < 8; ++i) hilo(v[i], hh[i], ll[i]);
    hi = make_uint4(hh[0] | (hh[1] << 16), hh[2] | (hh[3] << 16),
                    hh[4] | (hh[5] << 16), hh[6] | (hh[7] << 16));
    lo = make_uint4(ll[0] | (ll[1] << 16), ll[2] | (ll[3] << 16),
                    ll[4] | (ll[5] << 16), ll[6] | (ll[7] << 16));
}

__device__ __forceinline__ void pack4(const float* v, uint2& hi, uint2& lo) {
    unsigned hh[4], ll[4];
    #pragma unroll
    for (int i = 0; i < 4; ++i) hilo(v[i], hh[i], ll[i]);
    hi = make_uint2(hh[0] | (hh[1] << 16), hh[2] | (hh[3] << 16));
    lo = make_uint2(ll[0] | (ll[1] << 16), ll[2] | (ll[3] << 16));
}

// ---------------------------------------------------------------------------
// A-frag layout (K=KC*32): ushort buffer; block(rt,kc) at (rt*KC+kc)*1024,
// hi elem: lane*8 + i  (lane = (row%16) + ((k%32)/8)*16, i = k%8), lo at +512.
// GEMM reads 16B/lane fully coalesced.
// ---------------------------------------------------------------------------

// K_aprep: fp32 row-major [32768][128] -> frag hi/lo. grid 2048, block 256.
__global__ __launch_bounds__(256) void k_aprep(
    const float* __restrict__ src, unsigned short* __restrict__ dst)
{
    int idx = blockIdx.x * 256 + threadIdx.x;   // 32768*16
    int r = idx >> 4, k8 = (idx & 15) * 8;
    float t[8];
    *(float4*)(t)     = *(const float4*)(src + (size_t)r * 128 + k8);
    *(float4*)(t + 4) = *(const float4*)(src + (size_t)r * 128 + k8 + 4);
    uint4 hi, lo;
    pack8(t, hi, lo);
    int rt = r >> 4, kc = k8 >> 5, lp = (r & 15) + ((k8 & 31) >> 3) * 16;
    size_t base = ((size_t)rt * 4 + kc) * 1024 + lp * 8;
    *(uint4*)(dst + base)       = hi;
    *(uint4*)(dst + base + 512) = lo;
}

// ---------------------------------------------------------------------------
// K1: depthwise 3x3 conv (NHWC) + per-block partial BN sums
// ---------------------------------------------------------------------------
__global__ __launch_bounds__(256) void k_dwconv(
    const float* __restrict__ inp, const float* __restrict__ dww,
    const float* __restrict__ dwb, float* __restrict__ ydw,
    float* __restrict__ psum, float* __restrict__ psq)
{
    int blk = blockIdx.x;            // b*64 + h
    int b = blk >> 6, h = blk & 63;
    int tid = threadIdx.x;
    int c4 = (tid & 31) * 4;
    int wg = tid >> 5;               // 0..7

    float wreg[4][9];
    #pragma unroll
    for (int cc = 0; cc < 4; ++cc)
        #pragma unroll
        for (int p = 0; p < 9; ++p)
            wreg[cc][p] = dww[(c4 + cc) * 9 + p];
    float bia[4];
    #pragma unroll
    for (int cc = 0; cc < 4; ++cc) bia[cc] = dwb[c4 + cc];

    float s4[4] = {0,0,0,0}, q4[4] = {0,0,0,0};
    const float* ibase = inp + (size_t)(b << 12) * CDIM;

    for (int i = 0; i < 8; ++i) {
        int w = wg + i * 8;
        float acc[4] = {bia[0], bia[1], bia[2], bia[3]};
        #pragma unroll
        for (int ky = 0; ky < 3; ++ky) {
            int yy = h + ky - 1;
            if (yy < 0 || yy >= HS) continue;
            #pragma unroll
            for (int kx = 0; kx < 3; ++kx) {
                int xx = w + kx - 1;
                if (xx < 0 || xx >= WSZ) continue;
                float4 v = *(const float4*)(ibase + (size_t)(yy * 64 + xx) * CDIM + c4);
                int p = ky * 3 + kx;
                acc[0] += v.x * wreg[0][p];
                acc[1] += v.y * wreg[1][p];
                acc[2] += v.z * wreg[2][p];
                acc[3] += v.w * wreg[3][p];
            }
        }
        float4 o = {acc[0], acc[1], acc[2], acc[3]};
        *(float4*)(ydw + ((size_t)(b << 12) + h * 64 + w) * CDIM + c4) = o;
        #pragma unroll
        for (int cc = 0; cc < 4; ++cc) { s4[cc] += acc[cc]; q4[cc] += acc[cc] * acc[cc]; }
    }

    __shared__ float ls[8][128], lq[8][128];
    #pragma unroll
    for (int cc = 0; cc < 4; ++cc) { ls[wg][c4 + cc] = s4[cc]; lq[wg][c4 + cc] = q4[cc]; }
    __syncthreads();
    if (tid < 128) {
        float s = 0.f, q = 0.f;
        #pragma unroll
        for (int r = 0; r < 8; ++r) { s += ls[r][tid]; q += lq[r][tid]; }
        psum[blk * 128 + tid] = s;
        psq [blk * 128 + tid] = q;
    }
}

// ---------------------------------------------------------------------------
// K2: finalize BN stats -> scale/shift per channel.
// ---------------------------------------------------------------------------
__global__ __launch_bounds__(256) void k_bnstats(
    const float* __restrict__ psum, const float* __restrict__ psq,
    const float* __restrict__ gamma, const float* __restrict__ beta,
    float* __restrict__ sc, float* __restrict__ sh)
{
    int c = blockIdx.x;
    int t = threadIdx.x;
    float s = psum[t * 128 + c] + psum[(t + 256) * 128 + c];
    float q = psq [t * 128 + c] + psq [(t + 256) * 128 + c];
    __shared__ float rs[256], rq[256];
    rs[t] = s; rq[t] = q; __syncthreads();
    for (int off = 128; off > 0; off >>= 1) {
        if (t < off) { rs[t] += rs[t + off]; rq[t] += rq[t + off]; }
        __syncthreads();
    }
    if (t == 0) {
        float mean = rs[0] * (1.0f / 32768.0f);
        float var  = rq[0] * (1.0f / 32768.0f) - mean * mean;
        float scale = gamma[c] * rsqrtf(var + 1e-5f);
        sc[c] = scale;
        sh[c] = beta[c] - mean * scale;
    }
}

// ---------------------------------------------------------------------------
// K3: BN + exact GELU, ydw (fp32) -> x1 frag hi/lo. grid 2048, block 256.
// ---------------------------------------------------------------------------
__global__ __launch_bounds__(256) void k_bngelu(
    const float* __restrict__ ydw, const float* __restrict__ sc,
    const float* __restrict__ sh, unsigned short* __restrict__ dst)
{
    int idx = blockIdx.x * 256 + threadIdx.x;   // 32768*16
    int r = idx >> 4, k8 = (idx & 15) * 8;
    float t[8];
    *(float4*)(t)     = *(const float4*)(ydw + (size_t)r * 128 + k8);
    *(float4*)(t + 4) = *(const float4*)(ydw + (size_t)r * 128 + k8 + 4);
    float s[8], h[8];
    *(float4*)(s)     = *(const float4*)(sc + k8);
    *(float4*)(s + 4) = *(const float4*)(sc + k8 + 4);
    *(float4*)(h)     = *(const float4*)(sh + k8);
    *(float4*)(h + 4) = *(const float4*)(sh + k8 + 4);
    #pragma unroll
    for (int i = 0; i < 8; ++i) t[i] = gelu_exact(t[i] * s[i] + h[i]);
    uint4 hi, lo;
    pack8(t, hi, lo);
    int rt = r >> 4, kc = k8 >> 5, lp = (r & 15) + ((k8 & 31) >> 3) * 16;
    size_t base = ((size_t)rt * 4 + kc) * 1024 + lp * 8;
    *(uint4*)(dst + base)       = hi;
    *(uint4*)(dst + base + 512) = lo;
}

// ---------------------------------------------------------------------------
// K_wprep: weights W[N][K] fp32 -> fragment-ordered hi/lo bf16.
// ---------------------------------------------------------------------------
__global__ __launch_bounds__(64) void k_wprep(
    const float* __restrict__ w0, const float* __restrict__ w1,
    const float* __restrict__ w2, const float* __restrict__ w3,
    const float* __restrict__ w4, unsigned short* __restrict__ wb)
{
    int bid = blockIdx.x, lane = threadIdx.x;
    const float* W; int N, K, NT; unsigned short* out; int local;
    if (bid < 32)       { W = w0; N = 128; K = 128; NT = 8;  out = wb;          local = bid; }
    else if (bid < 68)  { W = w1; N = 144; K = 128; NT = 9;  out = wb + 32768;  local = bid - 32; }
    else if (bid < 88)  { W = w2; N = 72;  K = 128; NT = 5;  out = wb + 69632;  local = bid - 68; }
    else if (bid < 152) { W = w3; N = 256; K = 128; NT = 16; out = wb + 90112;  local = bid - 88; }
    else                { W = w4; N = 128; K = 256; NT = 8;  out = wb + 155648; local = bid - 152; }
    int KC = K / 32;
    int unit = KC * NT * 512;
    int kc = local / NT, t = local % NT;
    int n  = t * 16 + (lane & 15);
    int kb = kc * 32 + (lane >> 4) * 8;
    size_t base = ((size_t)local * 64 + lane) * 8;
    #pragma unroll
    for (int i = 0; i < 8; ++i) {
        float v = (n < N) ? W[(size_t)n * K + kb + i] : 0.f;
        __bf16 h = (__bf16)v;
        float  r = v - (float)h;
        __bf16 l = (__bf16)r;
        out[base + i]        = __builtin_bit_cast(unsigned short, h);
        out[unit + base + i] = __builtin_bit_cast(unsigned short, l);
    }
}

// ---------------------------------------------------------------------------
// Frag-stream MFMA GEMM. A and W both fragment-ordered hi/lo bf16 streams.
// wave = 1 rowtile (16 rows); block = 4 waves; grid 512 (2048 rowtiles).
// hi/lo split -> 3 MFMAs, ~fp32 accuracy. No LDS, no barriers.
// MODE 0: fp32 row-major C + bias.
// MODE 1: bias + GELU -> frag-only output OF (for fc2's A).
// MODE 2: bias -> fp32 NCHW transposed store.
// ---------------------------------------------------------------------------
template<int KDIM, int NT, int MODE, int NV>
__global__ __launch_bounds__(256) void k_fgemm(
    const unsigned short* __restrict__ AF, const unsigned short* __restrict__ WF,
    const float* __restrict__ bias, float* __restrict__ C, int ldc,
    unsigned short* __restrict__ OF)
{
    constexpr int KC = KDIM / 32;
    int tid = threadIdx.x;
    int lane = tid & 63, w = tid >> 6;
    int rt = blockIdx.x * 4 + w;        // rowtile 0..2047

    f32x4 acc[NT];
    #pragma unroll
    for (int t = 0; t < NT; ++t) acc[t] = (f32x4){0.f, 0.f, 0.f, 0.f};

    const bf8_t* Ab  = (const bf8_t*)AF + (size_t)rt * KC * 128 + lane;
    const bf8_t* WHp = (const bf8_t*)WF + lane;
    const bf8_t* WLp = WHp + KC * NT * 64;

    #pragma unroll
    for (int kc = 0; kc < KC; ++kc) {
        bf8_t ah = Ab[kc * 128];
        bf8_t al = Ab[kc * 128 + 64];
        #pragma unroll
        for (int t = 0; t < NT; ++t) {
            bf8_t wh = WHp[(kc * NT + t) * 64];
            bf8_t wl = WLp[(kc * NT + t) * 64];
            if (MODE == 2) {
                acc[t] = __builtin_amdgcn_mfma_f32_16x16x32_bf16(ah, wh, acc[t], 0, 0, 0);
                acc[t] = __builtin_amdgcn_mfma_f32_16x16x32_bf16(al, wh, acc[t], 0, 0, 0);
                acc[t] = __builtin_amdgcn_mfma_f32_16x16x32_bf16(ah, wl, acc[t], 0, 0, 0);
            } else {
                acc[t] = __builtin_amdgcn_mfma_f32_16x16x32_bf16(wh, ah, acc[t], 0, 0, 0);
                acc[t] = __builtin_amdgcn_mfma_f32_16x16x32_bf16(wh, al, acc[t], 0, 0, 0);
                acc[t] = __builtin_amdgcn_mfma_f32_16x16x32_bf16(wl, ah, acc[t], 0, 0, 0);
            }
        }
    }

    if (MODE == 0) {
        // lane: m = rt*16 + (lane&15), n = t*16 + (lane>>4)*4 + j
        int m = rt * 16 + (lane & 15);
        #pragma unroll
        for (int t = 0; t < NT; ++t) {
            int nb = t * 16 + ((lane >> 4) << 2);
            if (nb + 4 <= NV) {
                float4 bb = *(const float4*)(bias + nb);
                f32x4 a = acc[t];
                float4 v = {a[0] + bb.x, a[1] + bb.y, a[2] + bb.z, a[3] + bb.w};
                *(float4*)(C + (size_t)m * ldc + nb) = v;
            }
        }
    } else if (MODE == 1) {
        int m = rt * 16 + (lane & 15);
        #pragma unroll
        for (int t = 0; t < NT; ++t) {
            int nb = t * 16 + ((lane >> 4) << 2);
            float4 bb = *(const float4*)(bias + nb);
            f32x4 a = acc[t];
            float v[4];
            v[0] = gelu_exact(a[0] + bb.x); v[1] = gelu_exact(a[1] + bb.y);
            v[2] = gelu_exact(a[2] + bb.z); v[3] = gelu_exact(a[3] + bb.w);
            uint2 hi, lo;
            pack4(v, hi, lo);
            int kco = nb >> 5, lp = (m & 15) + ((nb & 31) >> 3) * 16;
            size_t fb = ((size_t)rt * (NV / 32) + kco) * 1024 + lp * 8 + (nb & 7);
            *(uint2*)(OF + fb)       = hi;
            *(uint2*)(OF + fb + 512) = lo;
        }
    } else {
        // lane: n = t*16 + (lane&15), m = rt*16 + (lane>>4)*4 + j
        int m4 = rt * 16 + ((lane >> 4) << 2);
        int b = m4 >> 12, hw = m4 & 4095;
        #pragma unroll
        for (int t = 0; t < NT; ++t) {
            int n = t * 16 + (lane & 15);
            float bb = bias[n];
            f32x4 a = acc[t];
            float4 v = {a[0] + bb, a[1] + bb, a[2] + bb, a[3] + bb};
            *(float4*)(C + (((size_t)(b * 128 + n)) << 12) + hw) = v;
        }
    }
}

// ---------------------------------------------------------------------------
// K6: DCNv3 core -> frag hi/lo output. grid 4096, block 256.
// ---------------------------------------------------------------------------
__global__ __launch_bounds__(256) void k_dcn(
    const float* __restrict__ xproj, const float* __restrict__ offs,
    const float* __restrict__ msk, unsigned short* __restrict__ dcnf)
{
    int u = blockIdx.x * 256 + threadIdx.x;  // N*G*4
    int q = u & 3;
    int pg = u >> 2;
    int g = pg & 7;
    int pos = pg >> 3;
    int b = pos >> 12, hw = pos & 4095, h = hw >> 6, w = hw & 63;

    const float* ml = msk + (size_t)pos * 72 + g * 9;
    float e[9];
    float mx = -1e30f;
    #pragma unroll
    for (int p = 0; p < 9; ++p) { e[p] = ml[p]; mx = fmaxf(mx, e[p]); }
    float ssum = 0.f;
    #pragma unroll
    for (int p = 0; p < 9; ++p) { e[p] = expf(e[p] - mx); ssum += e[p]; }
    float inv = 1.0f / ssum;

    const float* ob = offs + (size_t)pos * 144 + g * 18;
    int ch = g * 16 + q * 4;
    const float* xb = xproj + ch;
    size_t bbase = (size_t)(b << 12);

    float4 acc = {0.f, 0.f, 0.f, 0.f};
    #pragma unroll
    for (int p = 0; p < 9; ++p) {
        float dx = ob[p * 2 + 0];
        float dy = ob[p * 2 + 1];
        float px = (float)(w + (p % 3)) + dx;   // padded-space coords
        float py = (float)(h + (p / 3)) + dy;
        float x0f = floorf(px), y0f = floorf(py);
        float wx = px - x0f, wy = py - y0f;
        int ix = (int)x0f, iy = (int)y0f;

        float4 s00 = {0,0,0,0}, s01 = {0,0,0,0}, s10 = {0,0,0,0}, s11 = {0,0,0,0};
        bool y0v = (iy >= 1 && iy <= 64), y1v = (iy + 1 >= 1 && iy + 1 <= 64);
        bool x0v = (ix >= 1 && ix <= 64), x1v = (ix + 1 >= 1 && ix + 1 <= 64);
        if (y0v && x0v) s00 = *(const float4*)(xb + (bbase + (size_t)(iy - 1) * 64 + (ix - 1)) * 128);
        if (y0v && x1v) s01 = *(const float4*)(xb + (bbase + (size_t)(iy - 1) * 64 + ix) * 128);
        if (y1v && x0v) s10 = *(const float4*)(xb + (bbase + (size_t)iy * 64 + (ix - 1)) * 128);
        if (y1v && x1v) s11 = *(const float4*)(xb + (bbase + (size_t)iy * 64 + ix) * 128);

        float w00 = (1.f - wy) * (1.f - wx), w01 = (1.f - wy) * wx;
        float w10 = wy * (1.f - wx),         w11 = wy * wx;
        float mp = e[p] * inv;
        acc.x += mp * (s00.x * w00 + s01.x * w01 + s10.x * w10 + s11.x * w11);
        acc.y += mp * (s00.y * w00 + s01.y * w01 + s10.y * w10 + s11.y * w11);
        acc.z += mp * (s00.z * w00 + s01.z * w01 + s10.z * w10 + s11.z * w11);
        acc.w += mp * (s00.w * w00 + s01.w * w01 + s10.w * w10 + s11.w * w11);
    }

    float v[4] = {acc.x, acc.y, acc.z, acc.w};
    uint2 hi, lo;
    pack4(v, hi, lo);
    int rt = pos >> 4, kcf = ch >> 5, lp = (pos & 15) + ((ch & 31) >> 3) * 16;
    size_t fb = ((size_t)rt * 4 + kcf) * 1024 + lp * 8 + (ch & 7);
    *(uint2*)(dcnf + fb)       = hi;
    *(uint2*)(dcnf + fb + 512) = lo;
}

// ---------------------------------------------------------------------------
extern "C" void kernel_launch(void* const* d_in, const int* in_sizes, int n_in,
                              void* d_out, int out_size, void* d_ws, size_t ws_size,
                              hipStream_t stream)
{
    const float* inp   = (const float*)d_in[0];
    const float* wproj = (const float*)d_in[1];
    const float* bproj = (const float*)d_in[2];
    const float* dww   = (const float*)d_in[3];
    const float* dwb   = (const float*)d_in[4];
    const float* gamma = (const float*)d_in[5];
    const float* beta  = (const float*)d_in[6];
    const float* woff  = (const float*)d_in[7];
    const float* boff  = (const float*)d_in[8];
    const float* wmask = (const float*)d_in[9];
    const float* bmask = (const float*)d_in[10];
    const float* wfc1  = (const float*)d_in[11];
    const float* bfc1  = (const float*)d_in[12];
    const float* wfc2  = (const float*)d_in[13];
    const float* bfc2  = (const float*)d_in[14];
    float* out = (float*)d_out;
    float* ws  = (float*)d_ws;

    // Region P [0, 8912896): xproj + offs; later hdnf (fc1 out frags)
    float* xproj = ws;                                   // 4,194,304 f [proj..dcn]
    float* offs  = ws + 4194304;                         // 4,718,592 f [off..dcn]
    unsigned short* hdnf = (unsigned short*)ws;          // 16,777,216 ush [fc1..fc2]
    // Region A [8912896, 17301504): time-shared
    float* ydw            = ws + 8912896;                // 4,194,304 f [dwconv..bngelu]
    unsigned short* inpf  = (unsigned short*)(ws + 8912896);   // [aprep..proj]
    unsigned short* dcnf  = (unsigned short*)(ws + 8912896);   // [dcn..fc1]
    unsigned short* x1f   = (unsigned short*)(ws + 13107200);  // [bngelu..mask]
    // Rest
    float* msk  = ws + 17301504;                         // 2,359,296 f
    float* psum = ws + 19660800;                         // 65,536 f
    float* psq  = ws + 19726336;                         // 65,536 f
    float* scs  = ws + 19791872;                         // 128 f
    float* shs  = ws + 19792000;                         // 128 f
    unsigned short* wfr = (unsigned short*)(ws + 19792128);  // 221,184 ush

    unsigned short* wproj_f = wfr;
    unsigned short* woff_f  = wfr + 32768;
    unsigned short* wmask_f = wfr + 69632;
    unsigned short* wfc1_f  = wfr + 90112;
    unsigned short* wfc2_f  = wfr + 155648;

    k_wprep<<<216, 64, 0, stream>>>(wproj, woff, wmask, wfc1, wfc2, wfr);
    k_aprep<<<2048, 256, 0, stream>>>(inp, inpf);
    k_fgemm<128,  8, 0, 128><<<512, 256, 0, stream>>>(inpf, wproj_f, bproj, xproj, 128, nullptr);
    k_dwconv<<<512, 256, 0, stream>>>(inp, dww, dwb, ydw, psum, psq);
    k_bnstats<<<128, 256, 0, stream>>>(psum, psq, gamma, beta, scs, shs);
    k_bngelu<<<2048, 256, 0, stream>>>(ydw, scs, shs, x1f);
    k_fgemm<128,  9, 0, 144><<<512, 256, 0, stream>>>(x1f, woff_f, boff, offs, 144, nullptr);
    k_fgemm<128,  5, 0,  72><<<512, 256, 0, stream>>>(x1f, wmask_f, bmask, msk, 72, nullptr);
    k_dcn<<<4096, 256, 0, stream>>>(xproj, offs, msk, dcnf);
    k_fgemm<128, 16, 1, 256><<<512, 256, 0, stream>>>(dcnf, wfc1_f, bfc1, nullptr, 0, hdnf);
    k_fgemm<256,  8, 2, 128><<<512, 256, 0, stream>>>(hdnf, wfc2_f, bfc2, out, 0, nullptr);
}

// Round 4
// 157.549 us; speedup vs baseline: 1.4237x; 1.0805x over previous
//
#include <hip/hip_runtime.h>
#include <math.h>

#define NPOS  32768      // B*H*W
#define CDIM  128
#define HS    64
#define WSZ   64

typedef __bf16 bf8_t  __attribute__((ext_vector_type(8)));
typedef float  f32x4  __attribute__((ext_vector_type(4)));

__device__ __forceinline__ float gelu_exact(float x) {
    return 0.5f * x * (1.0f + erff(x * 0.70710678118654752f));
}

__device__ __forceinline__ void hilo(float v, unsigned& h, unsigned& l) {
    __bf16 hb = (__bf16)v;
    h = (unsigned)__builtin_bit_cast(unsigned short, hb);
    __bf16 lb = (__bf16)(v - (float)hb);
    l = (unsigned)__builtin_bit_cast(unsigned short, lb);
}

__device__ __forceinline__ void pack8(const float* v, uint4& hi, uint4& lo) {
    unsigned hh[8], ll[8];
    #pragma unroll
    for (int i = 0; i < 8; ++i) hilo(v[i], hh[i], ll[i]);
    hi = make_uint4(hh[0] | (hh[1] << 16), hh[2] | (hh[3] << 16),
                    hh[4] | (hh[5] << 16), hh[6] | (hh[7] << 16));
    lo = make_uint4(ll[0] | (ll[1] << 16), ll[2] | (ll[3] << 16),
                    ll[4] | (ll[5] << 16), ll[6] | (ll[7] << 16));
}

__device__ __forceinline__ void pack4(const float* v, uint2& hi, uint2& lo) {
    unsigned hh[4], ll[4];
    #pragma unroll
    for (int i = 0; i < 4; ++i) hilo(v[i], hh[i], ll[i]);
    hi = make_uint2(hh[0] | (hh[1] << 16), hh[2] | (hh[3] << 16));
    lo = make_uint2(ll[0] | (ll[1] << 16), ll[2] | (ll[3] << 16));
}

// ---------------------------------------------------------------------------
// A-frag layout (K=KC*32): ushort buffer; block(rt,kc) at (rt*KC+kc)*1024,
// hi elem: lane*8 + i  (lane = (row%16) + ((k%32)/8)*16, i = k%8), lo at +512.
// ---------------------------------------------------------------------------

// K_aprep: fp32 row-major [32768][128] -> frag hi/lo. grid 2048, block 256.
__global__ __launch_bounds__(256) void k_aprep(
    const float* __restrict__ src, unsigned short* __restrict__ dst)
{
    int idx = blockIdx.x * 256 + threadIdx.x;   // 32768*16
    int r = idx >> 4, k8 = (idx & 15) * 8;
    float t[8];
    *(float4*)(t)     = *(const float4*)(src + (size_t)r * 128 + k8);
    *(float4*)(t + 4) = *(const float4*)(src + (size_t)r * 128 + k8 + 4);
    uint4 hi, lo;
    pack8(t, hi, lo);
    int rt = r >> 4, kc = k8 >> 5, lp = (r & 15) + ((k8 & 31) >> 3) * 16;
    size_t base = ((size_t)rt * 4 + kc) * 1024 + lp * 8;
    *(uint4*)(dst + base)       = hi;
    *(uint4*)(dst + base + 512) = lo;
}

// ---------------------------------------------------------------------------
// K1: depthwise 3x3 conv (NHWC) + per-block partial BN sums
// ---------------------------------------------------------------------------
__global__ __launch_bounds__(256) void k_dwconv(
    const float* __restrict__ inp, const float* __restrict__ dww,
    const float* __restrict__ dwb, float* __restrict__ ydw,
    float* __restrict__ psum, float* __restrict__ psq)
{
    int blk = blockIdx.x;            // b*64 + h
    int b = blk >> 6, h = blk & 63;
    int tid = threadIdx.x;
    int c4 = (tid & 31) * 4;
    int wg = tid >> 5;               // 0..7

    float wreg[4][9];
    #pragma unroll
    for (int cc = 0; cc < 4; ++cc)
        #pragma unroll
        for (int p = 0; p < 9; ++p)
            wreg[cc][p] = dww[(c4 + cc) * 9 + p];
    float bia[4];
    #pragma unroll
    for (int cc = 0; cc < 4; ++cc) bia[cc] = dwb[c4 + cc];

    float s4[4] = {0,0,0,0}, q4[4] = {0,0,0,0};
    const float* ibase = inp + (size_t)(b << 12) * CDIM;

    for (int i = 0; i < 8; ++i) {
        int w = wg + i * 8;
        float acc[4] = {bia[0], bia[1], bia[2], bia[3]};
        #pragma unroll
        for (int ky = 0; ky < 3; ++ky) {
            int yy = h + ky - 1;
            if (yy < 0 || yy >= HS) continue;
            #pragma unroll
            for (int kx = 0; kx < 3; ++kx) {
                int xx = w + kx - 1;
                if (xx < 0 || xx >= WSZ) continue;
                float4 v = *(const float4*)(ibase + (size_t)(yy * 64 + xx) * CDIM + c4);
                int p = ky * 3 + kx;
                acc[0] += v.x * wreg[0][p];
                acc[1] += v.y * wreg[1][p];
                acc[2] += v.z * wreg[2][p];
                acc[3] += v.w * wreg[3][p];
            }
        }
        float4 o = {acc[0], acc[1], acc[2], acc[3]};
        *(float4*)(ydw + ((size_t)(b << 12) + h * 64 + w) * CDIM + c4) = o;
        #pragma unroll
        for (int cc = 0; cc < 4; ++cc) { s4[cc] += acc[cc]; q4[cc] += acc[cc] * acc[cc]; }
    }

    __shared__ float ls[8][128], lq[8][128];
    #pragma unroll
    for (int cc = 0; cc < 4; ++cc) { ls[wg][c4 + cc] = s4[cc]; lq[wg][c4 + cc] = q4[cc]; }
    __syncthreads();
    if (tid < 128) {
        float s = 0.f, q = 0.f;
        #pragma unroll
        for (int r = 0; r < 8; ++r) { s += ls[r][tid]; q += lq[r][tid]; }
        psum[blk * 128 + tid] = s;
        psq [blk * 128 + tid] = q;
    }
}

// ---------------------------------------------------------------------------
// K2: finalize BN stats -> scale/shift per channel.
// ---------------------------------------------------------------------------
__global__ __launch_bounds__(256) void k_bnstats(
    const float* __restrict__ psum, const float* __restrict__ psq,
    const float* __restrict__ gamma, const float* __restrict__ beta,
    float* __restrict__ sc, float* __restrict__ sh)
{
    int c = blockIdx.x;
    int t = threadIdx.x;
    float s = psum[t * 128 + c] + psum[(t + 256) * 128 + c];
    float q = psq [t * 128 + c] + psq [(t + 256) * 128 + c];
    __shared__ float rs[256], rq[256];
    rs[t] = s; rq[t] = q; __syncthreads();
    for (int off = 128; off > 0; off >>= 1) {
        if (t < off) { rs[t] += rs[t + off]; rq[t] += rq[t + off]; }
        __syncthreads();
    }
    if (t == 0) {
        float mean = rs[0] * (1.0f / 32768.0f);
        float var  = rq[0] * (1.0f / 32768.0f) - mean * mean;
        float scale = gamma[c] * rsqrtf(var + 1e-5f);
        sc[c] = scale;
        sh[c] = beta[c] - mean * scale;
    }
}

// ---------------------------------------------------------------------------
// K3: BN + exact GELU, ydw (fp32) -> x1 frag hi/lo. grid 2048, block 256.
// ---------------------------------------------------------------------------
__global__ __launch_bounds__(256) void k_bngelu(
    const float* __restrict__ ydw, const float* __restrict__ sc,
    const float* __restrict__ sh, unsigned short* __restrict__ dst)
{
    int idx = blockIdx.x * 256 + threadIdx.x;   // 32768*16
    int r = idx >> 4, k8 = (idx & 15) * 8;
    float t[8];
    *(float4*)(t)     = *(const float4*)(ydw + (size_t)r * 128 + k8);
    *(float4*)(t + 4) = *(const float4*)(ydw + (size_t)r * 128 + k8 + 4);
    float s[8], h[8];
    *(float4*)(s)     = *(const float4*)(sc + k8);
    *(float4*)(s + 4) = *(const float4*)(sc + k8 + 4);
    *(float4*)(h)     = *(const float4*)(sh + k8);
    *(float4*)(h + 4) = *(const float4*)(sh + k8 + 4);
    #pragma unroll
    for (int i = 0; i < 8; ++i) t[i] = gelu_exact(t[i] * s[i] + h[i]);
    uint4 hi, lo;
    pack8(t, hi, lo);
    int rt = r >> 4, kc = k8 >> 5, lp = (r & 15) + ((k8 & 31) >> 3) * 16;
    size_t base = ((size_t)rt * 4 + kc) * 1024 + lp * 8;
    *(uint4*)(dst + base)       = hi;
    *(uint4*)(dst + base + 512) = lo;
}

// ---------------------------------------------------------------------------
// K_wprep: weights W[N][K] fp32 -> fragment-ordered hi/lo bf16.
// ---------------------------------------------------------------------------
__global__ __launch_bounds__(64) void k_wprep(
    const float* __restrict__ w0, const float* __restrict__ w1,
    const float* __restrict__ w2, const float* __restrict__ w3,
    const float* __restrict__ w4, unsigned short* __restrict__ wb)
{
    int bid = blockIdx.x, lane = threadIdx.x;
    const float* W; int N, K, NT; unsigned short* out; int local;
    if (bid < 32)       { W = w0; N = 128; K = 128; NT = 8;  out = wb;          local = bid; }
    else if (bid < 68)  { W = w1; N = 144; K = 128; NT = 9;  out = wb + 32768;  local = bid - 32; }
    else if (bid < 88)  { W = w2; N = 72;  K = 128; NT = 5;  out = wb + 69632;  local = bid - 68; }
    else if (bid < 152) { W = w3; N = 256; K = 128; NT = 16; out = wb + 90112;  local = bid - 88; }
    else                { W = w4; N = 128; K = 256; NT = 8;  out = wb + 155648; local = bid - 152; }
    int KC = K / 32;
    int unit = KC * NT * 512;
    int kc = local / NT, t = local % NT;
    int n  = t * 16 + (lane & 15);
    int kb = kc * 32 + (lane >> 4) * 8;
    size_t base = ((size_t)local * 64 + lane) * 8;
    #pragma unroll
    for (int i = 0; i < 8; ++i) {
        float v = (n < N) ? W[(size_t)n * K + kb + i] : 0.f;
        __bf16 h = (__bf16)v;
        float  r = v - (float)h;
        __bf16 l = (__bf16)r;
        out[base + i]        = __builtin_bit_cast(unsigned short, h);
        out[unit + base + i] = __builtin_bit_cast(unsigned short, l);
    }
}

// ---------------------------------------------------------------------------
// Frag-stream MFMA GEMM, TLP+reuse version.
// grid: (rowtile_groups=256, n_chunks). block = 4 waves.
// wave = RT=2 rowtiles x NT_W n-tiles. All waves in a block share the n-chunk
// (L1 W reuse). hi/lo split -> 3 MFMAs, ~fp32 accuracy. No LDS, no barriers.
// MODE 0: fp32 row-major + bias. MODE 1: bias+GELU -> frag out. MODE 2: NCHW.
// ---------------------------------------------------------------------------
template<int KDIM, int NT_TOT, int NT_W, int MODE, int NV>
__global__ __launch_bounds__(256) void k_fgemm(
    const unsigned short* __restrict__ AF, const unsigned short* __restrict__ WF,
    const float* __restrict__ bias, float* __restrict__ C, int ldc,
    unsigned short* __restrict__ OF)
{
    constexpr int KC = KDIM / 32;
    int tid = threadIdx.x;
    int lane = tid & 63, w = tid >> 6;
    int rt0 = blockIdx.x * 8 + w * 2;      // 2 rowtiles per wave
    int t0 = blockIdx.y * NT_W;            // n-tile chunk base

    f32x4 acc[2][NT_W];
    #pragma unroll
    for (int rt = 0; rt < 2; ++rt)
        #pragma unroll
        for (int t = 0; t < NT_W; ++t) acc[rt][t] = (f32x4){0.f, 0.f, 0.f, 0.f};

    const bf8_t* Ab0 = (const bf8_t*)AF + (size_t)rt0 * KC * 128 + lane;
    const bf8_t* Ab1 = Ab0 + KC * 128;
    const bf8_t* WHp = (const bf8_t*)WF + lane;
    const bf8_t* WLp = WHp + KC * NT_TOT * 64;

    #pragma unroll
    for (int kc = 0; kc < KC; ++kc) {
        bf8_t a0h = Ab0[kc * 128];
        bf8_t a0l = Ab0[kc * 128 + 64];
        bf8_t a1h = Ab1[kc * 128];
        bf8_t a1l = Ab1[kc * 128 + 64];
        #pragma unroll
        for (int t = 0; t < NT_W; ++t) {
            int tg = t0 + t;
            if (tg < NT_TOT) {
                bf8_t wh = WHp[(kc * NT_TOT + tg) * 64];
                bf8_t wl = WLp[(kc * NT_TOT + tg) * 64];
                if (MODE == 2) {
                    acc[0][t] = __builtin_amdgcn_mfma_f32_16x16x32_bf16(a0h, wh, acc[0][t], 0, 0, 0);
                    acc[0][t] = __builtin_amdgcn_mfma_f32_16x16x32_bf16(a0l, wh, acc[0][t], 0, 0, 0);
                    acc[0][t] = __builtin_amdgcn_mfma_f32_16x16x32_bf16(a0h, wl, acc[0][t], 0, 0, 0);
                    acc[1][t] = __builtin_amdgcn_mfma_f32_16x16x32_bf16(a1h, wh, acc[1][t], 0, 0, 0);
                    acc[1][t] = __builtin_amdgcn_mfma_f32_16x16x32_bf16(a1l, wh, acc[1][t], 0, 0, 0);
                    acc[1][t] = __builtin_amdgcn_mfma_f32_16x16x32_bf16(a1h, wl, acc[1][t], 0, 0, 0);
                } else {
                    acc[0][t] = __builtin_amdgcn_mfma_f32_16x16x32_bf16(wh, a0h, acc[0][t], 0, 0, 0);
                    acc[0][t] = __builtin_amdgcn_mfma_f32_16x16x32_bf16(wh, a0l, acc[0][t], 0, 0, 0);
                    acc[0][t] = __builtin_amdgcn_mfma_f32_16x16x32_bf16(wl, a0h, acc[0][t], 0, 0, 0);
                    acc[1][t] = __builtin_amdgcn_mfma_f32_16x16x32_bf16(wh, a1h, acc[1][t], 0, 0, 0);
                    acc[1][t] = __builtin_amdgcn_mfma_f32_16x16x32_bf16(wh, a1l, acc[1][t], 0, 0, 0);
                    acc[1][t] = __builtin_amdgcn_mfma_f32_16x16x32_bf16(wl, a1h, acc[1][t], 0, 0, 0);
                }
            }
        }
    }

    #pragma unroll
    for (int rt = 0; rt < 2; ++rt) {
        if (MODE == 0) {
            int m = (rt0 + rt) * 16 + (lane & 15);
            #pragma unroll
            for (int t = 0; t < NT_W; ++t) {
                int tg = t0 + t;
                int nb = tg * 16 + ((lane >> 4) << 2);
                if (tg < NT_TOT && nb + 4 <= NV) {
                    float4 bb = *(const float4*)(bias + nb);
                    f32x4 a = acc[rt][t];
                    float4 v = {a[0] + bb.x, a[1] + bb.y, a[2] + bb.z, a[3] + bb.w};
                    *(float4*)(C + (size_t)m * ldc + nb) = v;
                }
            }
        } else if (MODE == 1) {
            int m = (rt0 + rt) * 16 + (lane & 15);
            #pragma unroll
            for (int t = 0; t < NT_W; ++t) {
                int tg = t0 + t;
                if (tg < NT_TOT) {
                    int nb = tg * 16 + ((lane >> 4) << 2);
                    float4 bb = *(const float4*)(bias + nb);
                    f32x4 a = acc[rt][t];
                    float v[4];
                    v[0] = gelu_exact(a[0] + bb.x); v[1] = gelu_exact(a[1] + bb.y);
                    v[2] = gelu_exact(a[2] + bb.z); v[3] = gelu_exact(a[3] + bb.w);
                    uint2 hi, lo;
                    pack4(v, hi, lo);
                    int kco = nb >> 5, lp = (m & 15) + ((nb & 31) >> 3) * 16;
                    size_t fb = ((size_t)(rt0 + rt) * (NV / 32) + kco) * 1024 + lp * 8 + (nb & 7);
                    *(uint2*)(OF + fb)       = hi;
                    *(uint2*)(OF + fb + 512) = lo;
                }
            }
        } else {
            int m4 = (rt0 + rt) * 16 + ((lane >> 4) << 2);
            int b = m4 >> 12, hw = m4 & 4095;
            #pragma unroll
            for (int t = 0; t < NT_W; ++t) {
                int tg = t0 + t;
                if (tg < NT_TOT) {
                    int n = tg * 16 + (lane & 15);
                    float bb = bias[n];
                    f32x4 a = acc[rt][t];
                    float4 v = {a[0] + bb, a[1] + bb, a[2] + bb, a[3] + bb};
                    *(float4*)(C + (((size_t)(b * 128 + n)) << 12) + hw) = v;
                }
            }
        }
    }
}

// ---------------------------------------------------------------------------
// K6: DCNv3 core -> frag hi/lo output. grid 4096, block 256.
// ---------------------------------------------------------------------------
__global__ __launch_bounds__(256) void k_dcn(
    const float* __restrict__ xproj, const float* __restrict__ offs,
    const float* __restrict__ msk, unsigned short* __restrict__ dcnf)
{
    int u = blockIdx.x * 256 + threadIdx.x;  // N*G*4
    int q = u & 3;
    int pg = u >> 2;
    int g = pg & 7;
    int pos = pg >> 3;
    int b = pos >> 12, hw = pos & 4095, h = hw >> 6, w = hw & 63;

    const float* ml = msk + (size_t)pos * 72 + g * 9;
    float e[9];
    float mx = -1e30f;
    #pragma unroll
    for (int p = 0; p < 9; ++p) { e[p] = ml[p]; mx = fmaxf(mx, e[p]); }
    float ssum = 0.f;
    #pragma unroll
    for (int p = 0; p < 9; ++p) { e[p] = expf(e[p] - mx); ssum += e[p]; }
    float inv = 1.0f / ssum;

    const float* ob = offs + (size_t)pos * 144 + g * 18;
    int ch = g * 16 + q * 4;
    const float* xb = xproj + ch;
    size_t bbase = (size_t)(b << 12);

    float4 acc = {0.f, 0.f, 0.f, 0.f};
    #pragma unroll
    for (int p = 0; p < 9; ++p) {
        float dx = ob[p * 2 + 0];
        float dy = ob[p * 2 + 1];
        float px = (float)(w + (p % 3)) + dx;   // padded-space coords
        float py = (float)(h + (p / 3)) + dy;
        float x0f = floorf(px), y0f = floorf(py);
        float wx = px - x0f, wy = py - y0f;
        int ix = (int)x0f, iy = (int)y0f;

        float4 s00 = {0,0,0,0}, s01 = {0,0,0,0}, s10 = {0,0,0,0}, s11 = {0,0,0,0};
        bool y0v = (iy >= 1 && iy <= 64), y1v = (iy + 1 >= 1 && iy + 1 <= 64);
        bool x0v = (ix >= 1 && ix <= 64), x1v = (ix + 1 >= 1 && ix + 1 <= 64);
        if (y0v && x0v) s00 = *(const float4*)(xb + (bbase + (size_t)(iy - 1) * 64 + (ix - 1)) * 128);
        if (y0v && x1v) s01 = *(const float4*)(xb + (bbase + (size_t)(iy - 1) * 64 + ix) * 128);
        if (y1v && x0v) s10 = *(const float4*)(xb + (bbase + (size_t)iy * 64 + (ix - 1)) * 128);
        if (y1v && x1v) s11 = *(const float4*)(xb + (bbase + (size_t)iy * 64 + ix) * 128);

        float w00 = (1.f - wy) * (1.f - wx), w01 = (1.f - wy) * wx;
        float w10 = wy * (1.f - wx),         w11 = wy * wx;
        float mp = e[p] * inv;
        acc.x += mp * (s00.x * w00 + s01.x * w01 + s10.x * w10 + s11.x * w11);
        acc.y += mp * (s00.y * w00 + s01.y * w01 + s10.y * w10 + s11.y * w11);
        acc.z += mp * (s00.z * w00 + s01.z * w01 + s10.z * w10 + s11.z * w11);
        acc.w += mp * (s00.w * w00 + s01.w * w01 + s10.w * w10 + s11.w * w11);
    }

    float v[4] = {acc.x, acc.y, acc.z, acc.w};
    uint2 hi, lo;
    pack4(v, hi, lo);
    int rt = pos >> 4, kcf = ch >> 5, lp = (pos & 15) + ((ch & 31) >> 3) * 16;
    size_t fb = ((size_t)rt * 4 + kcf) * 1024 + lp * 8 + (ch & 7);
    *(uint2*)(dcnf + fb)       = hi;
    *(uint2*)(dcnf + fb + 512) = lo;
}

// ---------------------------------------------------------------------------
extern "C" void kernel_launch(void* const* d_in, const int* in_sizes, int n_in,
                              void* d_out, int out_size, void* d_ws, size_t ws_size,
                              hipStream_t stream)
{
    const float* inp   = (const float*)d_in[0];
    const float* wproj = (const float*)d_in[1];
    const float* bproj = (const float*)d_in[2];
    const float* dww   = (const float*)d_in[3];
    const float* dwb   = (const float*)d_in[4];
    const float* gamma = (const float*)d_in[5];
    const float* beta  = (const float*)d_in[6];
    const float* woff  = (const float*)d_in[7];
    const float* boff  = (const float*)d_in[8];
    const float* wmask = (const float*)d_in[9];
    const float* bmask = (const float*)d_in[10];
    const float* wfc1  = (const float*)d_in[11];
    const float* bfc1  = (const float*)d_in[12];
    const float* wfc2  = (const float*)d_in[13];
    const float* bfc2  = (const float*)d_in[14];
    float* out = (float*)d_out;
    float* ws  = (float*)d_ws;

    // Region P [0, 8912896): xproj + offs; later hdnf (fc1 out frags)
    float* xproj = ws;                                   // 4,194,304 f [proj..dcn]
    float* offs  = ws + 4194304;                         // 4,718,592 f [off..dcn]
    unsigned short* hdnf = (unsigned short*)ws;          // 16,777,216 ush [fc1..fc2]
    // Region A [8912896, 17301504): time-shared
    float* ydw            = ws + 8912896;                // 4,194,304 f [dwconv..bngelu]
    unsigned short* inpf  = (unsigned short*)(ws + 8912896);   // [aprep..proj]
    unsigned short* dcnf  = (unsigned short*)(ws + 8912896);   // [dcn..fc1]
    unsigned short* x1f   = (unsigned short*)(ws + 13107200);  // [bngelu..mask]
    // Rest
    float* msk  = ws + 17301504;                         // 2,359,296 f
    float* psum = ws + 19660800;                         // 65,536 f
    float* psq  = ws + 19726336;                         // 65,536 f
    float* scs  = ws + 19791872;                         // 128 f
    float* shs  = ws + 19792000;                         // 128 f
    unsigned short* wfr = (unsigned short*)(ws + 19792128);  // 221,184 ush

    unsigned short* wproj_f = wfr;
    unsigned short* woff_f  = wfr + 32768;
    unsigned short* wmask_f = wfr + 69632;
    unsigned short* wfc1_f  = wfr + 90112;
    unsigned short* wfc2_f  = wfr + 155648;

    k_wprep<<<216, 64, 0, stream>>>(wproj, woff, wmask, wfc1, wfc2, wfr);
    k_aprep<<<2048, 256, 0, stream>>>(inp, inpf);
    k_fgemm<128,  8, 2, 0, 128><<<dim3(256, 4), 256, 0, stream>>>(inpf, wproj_f, bproj, xproj, 128, nullptr);
    k_dwconv<<<512, 256, 0, stream>>>(inp, dww, dwb, ydw, psum, psq);
    k_bnstats<<<128, 256, 0, stream>>>(psum, psq, gamma, beta, scs, shs);
    k_bngelu<<<2048, 256, 0, stream>>>(ydw, scs, shs, x1f);
    k_fgemm<128,  9, 3, 0, 144><<<dim3(256, 3), 256, 0, stream>>>(x1f, woff_f, boff, offs, 144, nullptr);
    k_fgemm<128,  5, 3, 0,  72><<<dim3(256, 2), 256, 0, stream>>>(x1f, wmask_f, bmask, msk, 72, nullptr);
    k_dcn<<<4096, 256, 0, stream>>>(xproj, offs, msk, dcnf);
    k_fgemm<128, 16, 4, 1, 256><<<dim3(256, 4), 256, 0, stream>>>(dcnf, wfc1_f, bfc1, nullptr, 0, hdnf);
    k_fgemm<256,  8, 2, 2, 128><<<dim3(256, 4), 256, 0, stream>>>(hdnf, wfc2_f, bfc2, out, 0, nullptr);
}